// Round 2
// baseline (7975.218 us; speedup 1.0000x reference)
//
#include <hip/hip_runtime.h>

#define B_   1024
#define S_   168
#define F_   64
#define I_   128
#define H_   512
#define G4   2048
#define PRED 24

typedef unsigned short u16;
typedef unsigned int   u32;
typedef __attribute__((ext_vector_type(8))) __bf16 bf16x8;
typedef __attribute__((ext_vector_type(4))) float  f32x4;
typedef __attribute__((ext_vector_type(4))) int    i32x4;

__device__ __forceinline__ u16 f2bf(float f) {
  u32 u = __float_as_uint(f);
  u += 0x7fff + ((u >> 16) & 1);
  return (u16)(u >> 16);
}
__device__ __forceinline__ float bf2f(u16 h) {
  return __uint_as_float(((u32)h) << 16);
}
__device__ __forceinline__ float sigm(float x) {
  x = fminf(fmaxf(x, -30.f), 30.f);
  return 1.f / (1.f + __expf(-x));
}
__device__ __forceinline__ float tanh_(float x) {
  x = fminf(fmaxf(x, -15.f), 15.f);
  float e = __expf(2.f * x);
  return (e - 1.f) / (e + 1.f);
}

// ---------------- prep kernels ----------------

__global__ void k_split(const float* __restrict__ src, u16* __restrict__ hi,
                        u16* __restrict__ lo, int n) {
  for (int i = blockIdx.x * 256 + threadIdx.x; i < n; i += gridDim.x * 256) {
    float a = src[i];
    u16 h = f2bf(a);
    hi[i] = h;
    lo[i] = f2bf(a - bf2f(h));
  }
}

__global__ void k_w0c(const float* __restrict__ Wih0, const float* __restrict__ Wenc,
                      float* __restrict__ W0c) {
  int id = blockIdx.x * 256 + threadIdx.x;
  int j = id >> 6, f = id & 63;
  float s = 0.f;
  for (int i = 0; i < 128; ++i) s += Wih0[j * 128 + i] * Wenc[i * 64 + f];
  W0c[id] = s;
}

__global__ void k_w0cd(const float* __restrict__ W0c, const float* __restrict__ Wdec,
                       float* __restrict__ W0cd) {
  int id = blockIdx.x * 256 + threadIdx.x;
  int j = id >> 9, m = id & 511;
  float s = 0.f;
  for (int f = 0; f < 64; ++f) s += W0c[j * 64 + f] * Wdec[f * 512 + m];
  W0cd[id] = s;
}

__global__ void k_biases(const float* __restrict__ Wih0, const float* __restrict__ benc,
                         const float* __restrict__ bih0, const float* __restrict__ bhh0,
                         const float* __restrict__ bih1, const float* __restrict__ bhh1,
                         float* __restrict__ b0c, float* __restrict__ b1c) {
  int j = blockIdx.x * 256 + threadIdx.x;
  float s = 0.f;
  for (int i = 0; i < 128; ++i) s += Wih0[j * 128 + i] * benc[i];
  b0c[j] = s + bih0[j] + bhh0[j];
  b1c[j] = bih1[j] + bhh1[j];
}

__global__ void k_b0ar(const float* __restrict__ W0c, const float* __restrict__ bdec,
                       const float* __restrict__ b0c, float* __restrict__ b0ar) {
  int j = blockIdx.x * 256 + threadIdx.x;
  float s = 0.f;
  for (int f = 0; f < 64; ++f) s += W0c[j * 64 + f] * bdec[f];
  b0ar[j] = b0c[j] + s;
}

// Pack W [2048 x K] row-major (row = g*512 + j) into MFMA B-fragment stream:
// frag fi = (jt16*4 + g)*NK + kt -> 2KB: [0,1KB)=hi, [1KB,2KB)=lo.
__global__ void k_pack(const float* __restrict__ W, int K, u16* __restrict__ dst) {
  int id = blockIdx.x * 256 + threadIdx.x;
  int lane = id & 63, fi = id >> 6;
  int NK = K >> 5;
  int kt = fi % NK, jg = fi / NK;
  int g = jg & 3, jt = jg >> 2;
  int j = jt * 16 + (lane & 15);
  int kb = kt * 32 + (lane >> 4) * 8;
  const float* src = W + (size_t)(g * 512 + j) * K + kb;
  u16 hi[8] __attribute__((aligned(16)));
  u16 lo[8] __attribute__((aligned(16)));
#pragma unroll
  for (int e = 0; e < 8; ++e) {
    float v = src[e];
    u16 h = f2bf(v);
    hi[e] = h;
    lo[e] = f2bf(v - bf2f(h));
  }
  u16* d = dst + (size_t)fi * 1024 + lane * 8;
  *(i32x4*)d = *(const i32x4*)hi;
  *(i32x4*)(d + 512) = *(const i32x4*)lo;
}

// ---------------- fused GEMM + LSTM-cell body (v3, unchanged math) ----------------
// WG tile [64m x 32j x 4g]; 8 waves = 4 kk (K-split) x 2 jh.
// Wave tile [64m x 16j x 4g] over a K-quarter: W frags reused across 4 m-tiles
// in registers. Partial accs reduced via LDS.

struct CellArgs {
  const u16* A1hi; const u16* A1lo; int strideA1; int K1;
  const u16* W1p;
  const u16* A2hi; const u16* A2lo;
  const u16* W2p;
  const float* bias;
  float* c;
  u16* hhi; u16* hlo;
};

struct DecArgs {
  const u16* hhi; const u16* hlo;
  const float* Wdec; const float* bdec;
  float* out;
};

__device__ __forceinline__ void cell_body(const CellArgs& P, u16* smem_,
                                          int t, int jblk, int mblk) {
  const u16* __restrict__ A1hi = P.A1hi;
  const u16* __restrict__ A1lo = P.A1lo;
  const int strideA1 = P.strideA1;
  const int K1 = P.K1;
  const u16* __restrict__ W1p = P.W1p;
  const u16* __restrict__ A2hi = P.A2hi;
  const u16* __restrict__ A2lo = P.A2lo;
  const u16* __restrict__ W2p = P.W2p;
  const float* __restrict__ bias = P.bias;
  float* __restrict__ c = P.c;
  u16* __restrict__ hhi = P.hhi;
  u16* __restrict__ hlo = P.hlo;

  const int mbase = mblk * 64;
  const int lane = t & 63, wv = t >> 6;
  const int kk = wv >> 1, jh = wv & 1;       // K-split id, j-half id
  const int lr = lane & 15, qk = lane >> 4;
  const int jtg = jblk * 2 + jh;
  const int nc1 = (K1 == 64) ? 1 : 4;
  const int NC  = nc1 + 4;
  const int NK1 = K1 >> 5;

  f32x4 acc[4][4];   // [mi][gate]
#pragma unroll
  for (int mi = 0; mi < 4; ++mi)
#pragma unroll
    for (int g = 0; g < 4; ++g) acc[mi][g] = (f32x4){0.f, 0.f, 0.f, 0.f};

  auto prm = [&](int cc, const u16*& Ah, const u16*& Al, int& st, int& kb, int& Kc,
                 const u16*& Wp, int& NK) {
    if (cc < nc1) { Ah = A1hi; Al = A1lo; st = strideA1; kb = cc * 128;
                    Kc = (K1 == 64) ? 64 : 128; Wp = W1p; NK = NK1; }
    else { int i = cc - nc1; Ah = A2hi; Al = A2lo; st = 512; kb = i * 128;
           Kc = 128; Wp = W2p; NK = 16; }
  };
  auto nsof = [&](int cc) { return (cc < nc1 && K1 == 64) ? 2 : 4; };

  auto stageLoad = [&](int cc, i32x4* rr) {
    const u16 *Ah, *Al, *Wp_; int st, kb, Kc, NK;
    prm(cc, Ah, Al, st, kb, Kc, Wp_, NK);
    const int ppr = Kc >> 3;
    const int npc = (Kc == 128) ? 4 : 2;
#pragma unroll 4
    for (int p = 0; p < npc; ++p) {
      int li   = p * 512 + t;
      int part = li >= 64 * ppr;
      int liw  = li - part * 64 * ppr;
      int rown = (ppr == 16) ? (liw >> 4) : (liw >> 3);
      int kp   = liw & (ppr - 1);
      const u16* src = (part ? Al : Ah) + (size_t)(mbase + rown) * st + kb + kp * 8;
      rr[p] = *(const i32x4*)src;
    }
  };
  auto stageWrite = [&](int cc, const i32x4* rr, int buf) {
    const int Kc  = (cc < nc1 && K1 == 64) ? 64 : 128;
    const int ppr = Kc >> 3;
    const int npc = (Kc == 128) ? 4 : 2;
    u16* sb = smem_ + buf * 16384;
#pragma unroll 4
    for (int p = 0; p < npc; ++p) {
      int li   = p * 512 + t;
      int part = li >= 64 * ppr;
      int liw  = li - part * 64 * ppr;
      int rown = (ppr == 16) ? (liw >> 4) : (liw >> 3);
      int kp   = liw & (ppr - 1);
      *(i32x4*)&sb[(((part * 64 + rown) * ppr) + (kp ^ (rown & (ppr - 1)))) * 8] = rr[p];
    }
  };
  auto loadW = [&](const u16* Wp_, int NK, int kt, i32x4* wh, i32x4* wl) {
#pragma unroll
    for (int g = 0; g < 4; ++g) {
      const u16* p = Wp_ + (size_t)((jtg * 4 + g) * NK + kt) * 1024 + lane * 8;
      wh[g] = *(const i32x4*)p;
      wl[g] = *(const i32x4*)(p + 512);
    }
  };
  auto mstep = [&](int buf, int ppr, const i32x4* wh, const i32x4* wl) {
    const u16* sb = smem_ + buf * 16384;
    bf16x8 ah[4], al[4];
#pragma unroll
    for (int mi = 0; mi < 4; ++mi) {
      int rowA = mi * 16 + lr;
      int pl   = (kk * 4 + qk) ^ (rowA & (ppr - 1));
      ah[mi] = *(const bf16x8*)&sb[(rowA * ppr + pl) * 8];
      al[mi] = *(const bf16x8*)&sb[((64 + rowA) * ppr + pl) * 8];
    }
#pragma unroll
    for (int g = 0; g < 4; ++g) {
      bf16x8 bh = __builtin_bit_cast(bf16x8, wh[g]);
      bf16x8 bl = __builtin_bit_cast(bf16x8, wl[g]);
#pragma unroll
      for (int mi = 0; mi < 4; ++mi) {
        acc[mi][g] = __builtin_amdgcn_mfma_f32_16x16x32_bf16(ah[mi], bh, acc[mi][g], 0, 0, 0);
        acc[mi][g] = __builtin_amdgcn_mfma_f32_16x16x32_bf16(al[mi], bh, acc[mi][g], 0, 0, 0);
        acc[mi][g] = __builtin_amdgcn_mfma_f32_16x16x32_bf16(ah[mi], bl, acc[mi][g], 0, 0, 0);
      }
    }
  };

  i32x4 sreg[4];
  i32x4 whA[4], wlA[4], whB[4], wlB[4];

  stageLoad(0, sreg);
  stageWrite(0, sreg, 0);
  {
    const u16 *Ah, *Al, *Wp_; int st, kb, Kc, NK;
    prm(0, Ah, Al, st, kb, Kc, Wp_, NK);
    if (kk < nsof(0)) loadW(Wp_, NK, (kb >> 5) + kk, whA, wlA);
  }
  __syncthreads();

  for (int cc = 0; cc < NC; ++cc) {
    const int buf  = cc & 1;
    const bool more = (cc + 1 < NC);
    if (more) {
      stageLoad(cc + 1, sreg);
      const u16 *Ah, *Al, *Wp_; int st, kb, Kc, NK;
      prm(cc + 1, Ah, Al, st, kb, Kc, Wp_, NK);
      if (kk < nsof(cc + 1)) loadW(Wp_, NK, (kb >> 5) + kk, whB, wlB);
    }
    {
      const u16 *Ah, *Al, *Wp_; int st, kb, Kc, NK;
      prm(cc, Ah, Al, st, kb, Kc, Wp_, NK);
      if (kk < nsof(cc)) mstep(buf, Kc >> 3, whA, wlA);
    }
    if (more) stageWrite(cc + 1, sreg, buf ^ 1);
    __syncthreads();
    if (more) {
#pragma unroll
      for (int g = 0; g < 4; ++g) { whA[g] = whB[g]; wlA[g] = wlB[g]; }
    }
  }

  // ---- 4-way K-split reduction through LDS ----
  float* red = (float*)smem_;
#pragma unroll
  for (int mi = 0; mi < 4; ++mi) {
    if (mi != kk) {
      int slot = kk - (kk > mi ? 1 : 0);
      float* base = red + (size_t)(((jh * 4 + mi) * 3 + slot) * 1024) + lane * 4;
#pragma unroll
      for (int g = 0; g < 4; ++g) *(f32x4*)(base + g * 256) = acc[mi][g];
    }
  }
  __syncthreads();

  f32x4 r[4];
#pragma unroll
  for (int g = 0; g < 4; ++g) r[g] = acc[0][g];
  if (kk == 1) {
#pragma unroll
    for (int g = 0; g < 4; ++g) r[g] = acc[1][g];
  } else if (kk == 2) {
#pragma unroll
    for (int g = 0; g < 4; ++g) r[g] = acc[2][g];
  } else if (kk == 3) {
#pragma unroll
    for (int g = 0; g < 4; ++g) r[g] = acc[3][g];
  }
#pragma unroll
  for (int s = 0; s < 3; ++s) {
    float* base = red + (size_t)(((jh * 4 + kk) * 3 + s) * 1024) + lane * 4;
#pragma unroll
    for (int g = 0; g < 4; ++g) r[g] += *(const f32x4*)(base + g * 256);
  }

  // ---- epilogue: owner wave (kk,jh) covers m-tile mi=kk, j-half jh ----
  const int   j   = jblk * 32 + jh * 16 + lr;
  const float bi  = bias[j];
  const float bff = bias[512 + j];
  const float bg  = bias[1024 + j];
  const float bo  = bias[1536 + j];
#pragma unroll
  for (int rr = 0; rr < 4; ++rr) {
    int b   = mbase + kk * 16 + qk * 4 + rr;
    int idx = b * 512 + j;
    float iv = sigm(r[0][rr] + bi);
    float fv = sigm(r[1][rr] + bff);
    float gv = tanh_(r[2][rr] + bg);
    float ov = sigm(r[3][rr] + bo);
    float cn = fv * c[idx] + iv * gv;
    c[idx] = cn;
    float hn = ov * tanh_(cn);
    u16 hh = f2bf(hn);
    hhi[idx] = hh;
    hlo[idx] = f2bf(hn - bf2f(hh));
  }
}

// ---------------- decoder body (512-thread variant) ----------------
__device__ __forceinline__ void dec_body(const DecArgs& D, float* smemf,
                                         int t, int bx, int by) {
  if (by >= 8) return;               // whole block exits before any barrier
  float (*sH)[65] = (float (*)[65])smemf;
  const int bbase = bx * 64;
  const int mbase = by * 64;
  {
    int b  = bbase + (t >> 3);
    int m0 = (t & 7) * 8;
    i32x4 hv = *(const i32x4*)&D.hhi[(size_t)b * 512 + mbase + m0];
    i32x4 lv = *(const i32x4*)&D.hlo[(size_t)b * 512 + mbase + m0];
    const u16* hp = (const u16*)&hv;
    const u16* lp = (const u16*)&lv;
#pragma unroll
    for (int e = 0; e < 8; ++e)
      sH[t >> 3][m0 + e] = bf2f(hp[e]) + bf2f(lp[e]);
  }
  __syncthreads();
  const int bl = t & 63;
  const int wv = t >> 6;             // 8 f-groups
  float acc[8];
#pragma unroll
  for (int u = 0; u < 8; ++u) acc[u] = 0.f;
  for (int m = 0; m < 64; ++m) {
    float hv = sH[bl][m];
#pragma unroll
    for (int u = 0; u < 8; ++u)
      acc[u] += hv * D.Wdec[(size_t)(u * 8 + wv) * 512 + mbase + m];
  }
#pragma unroll
  for (int u = 0; u < 8; ++u) {
    int f = u * 8 + wv;
    float v = acc[u];
    if (by == 0) v += D.bdec[f];
    atomicAdd(&D.out[(size_t)(bbase + bl) * (PRED * F_) + f], v);
  }
}

// ---------------- kernels ----------------

__global__ __launch_bounds__(512, 2) void lstm3(CellArgs a) {
  __shared__ __align__(16) u16 smem_[49152];
  cell_body(a, smem_, threadIdx.x, blockIdx.x, blockIdx.y);
}

// z=0: cell a0 (long job, dispatched first); z=1: cell a1.
__global__ __launch_bounds__(512, 2) void lstm3_dual(CellArgs a0, CellArgs a1) {
  __shared__ __align__(16) u16 smem_[49152];
  if (blockIdx.z == 0) cell_body(a0, smem_, threadIdx.x, blockIdx.x, blockIdx.y);
  else                 cell_body(a1, smem_, threadIdx.x, blockIdx.x, blockIdx.y);
}

// z=0: cell (long job); z=1: decoder plane (blocks with by>=8 exit immediately).
__global__ __launch_bounds__(512, 2) void lstm3_cell_dec(CellArgs a, DecArgs d) {
  __shared__ __align__(16) u16 smem_[49152];
  if (blockIdx.z == 0) cell_body(a, smem_, threadIdx.x, blockIdx.x, blockIdx.y);
  else                 dec_body(d, (float*)smem_, threadIdx.x, blockIdx.x, blockIdx.y);
}

__global__ __launch_bounds__(512) void k_decoder2(DecArgs d) {
  __shared__ __align__(16) float sm[64 * 65];
  dec_body(d, sm, threadIdx.x, blockIdx.x, blockIdx.y);
}

// ---------------- host orchestration ----------------

extern "C" void kernel_launch(void* const* d_in, const int* in_sizes, int n_in,
                              void* d_out, int out_size, void* d_ws, size_t ws_size,
                              hipStream_t stream) {
  const float* x    = (const float*)d_in[0];
  const float* Wenc = (const float*)d_in[1];
  const float* benc = (const float*)d_in[2];
  const float* Wih0 = (const float*)d_in[3];
  const float* Whh0 = (const float*)d_in[4];
  const float* bih0 = (const float*)d_in[5];
  const float* bhh0 = (const float*)d_in[6];
  const float* Wih1 = (const float*)d_in[7];
  const float* Whh1 = (const float*)d_in[8];
  const float* bih1 = (const float*)d_in[9];
  const float* bhh1 = (const float*)d_in[10];
  const float* Wdec = (const float*)d_in[11];
  const float* bdec = (const float*)d_in[12];
  float* out = (float*)d_out;

  char* p = (char*)d_ws;
  auto carve = [&](size_t bytes) { char* r = p; p += (bytes + 255) & ~(size_t)255; return r; };
  const size_t NX = (size_t)B_ * S_ * F_;
  const size_t NH = (size_t)B_ * H_;
  const size_t WP512 = (size_t)G4 * 512 * 2;
  u16* Xhi    = (u16*)carve(NX * 2);
  u16* Xlo    = (u16*)carve(NX * 2);
  float* W0c  = (float*)carve((size_t)G4 * 64 * 4);
  float* W0cd = (float*)carve((size_t)G4 * 512 * 4);
  u16* W0cp   = (u16*)carve((size_t)G4 * 64 * 2 * 2);
  u16* W0cdp  = (u16*)carve(WP512 * 2);
  u16* Whh0p  = (u16*)carve(WP512 * 2);
  u16* Wih1p  = (u16*)carve(WP512 * 2);
  u16* Whh1p  = (u16*)carve(WP512 * 2);
  float* b0c  = (float*)carve(G4 * 4);
  float* b0ar = (float*)carve(G4 * 4);
  float* b1c  = (float*)carve(G4 * 4);
  u16* h0hi[2] = {(u16*)carve(NH * 2), (u16*)carve(NH * 2)};
  u16* h0lo[2] = {(u16*)carve(NH * 2), (u16*)carve(NH * 2)};
  u16* h1hi[2] = {(u16*)carve(NH * 2), (u16*)carve(NH * 2)};
  u16* h1lo[2] = {(u16*)carve(NH * 2), (u16*)carve(NH * 2)};
  float* c0 = (float*)carve(NH * 4);
  float* c1 = (float*)carve(NH * 4);
  (void)ws_size; (void)n_in; (void)in_sizes;

  hipMemsetAsync(d_out, 0, (size_t)out_size * 4, stream);
  hipMemsetAsync(h0hi[0], 0, NH * 2, stream);
  hipMemsetAsync(h0lo[0], 0, NH * 2, stream);
  hipMemsetAsync(h1hi[0], 0, NH * 2, stream);
  hipMemsetAsync(h1lo[0], 0, NH * 2, stream);
  hipMemsetAsync(c0, 0, NH * 4, stream);
  hipMemsetAsync(c1, 0, NH * 4, stream);

  k_split<<<4096, 256, 0, stream>>>(x, Xhi, Xlo, (int)NX);
  k_w0c<<<512, 256, 0, stream>>>(Wih0, Wenc, W0c);
  k_w0cd<<<4096, 256, 0, stream>>>(W0c, Wdec, W0cd);
  k_biases<<<8, 256, 0, stream>>>(Wih0, benc, bih0, bhh0, bih1, bhh1, b0c, b1c);
  k_b0ar<<<8, 256, 0, stream>>>(W0c, bdec, b0c, b0ar);
  k_pack<<<32 * 16, 256, 0, stream>>>(Whh0, 512, Whh0p);
  k_pack<<<32 * 16, 256, 0, stream>>>(Wih1, 512, Wih1p);
  k_pack<<<32 * 16, 256, 0, stream>>>(Whh1, 512, Whh1p);
  k_pack<<<32 * 16, 256, 0, stream>>>(W0cd, 512, W0cdp);
  k_pack<<<32 * 2, 256, 0, stream>>>(W0c, 64, W0cp);

  dim3 grid(16, 16);
  dim3 grid2(16, 16, 2);

  // ---- teacher-forced phase ----
  // L0(0):  pp=0,np=1 — reads h0[0], writes h0[1]
  {
    CellArgs l0 = {Xhi, Xlo, S_ * F_, 64, W0cp,
                   h0hi[0], h0lo[0], Whh0p, b0c, c0, h0hi[1], h0lo[1]};
    lstm3<<<grid, 512, 0, stream>>>(l0);
  }
  // fused: { L1(s) , L0(s+1) } — both depend only on outputs of the previous launch
  for (int s = 0; s < S_ - 1; ++s) {
    int pp = s & 1, np = 1 - pp;
    CellArgs l1 = {h0hi[np], h0lo[np], 512, 512, Wih1p,
                   h1hi[pp], h1lo[pp], Whh1p, b1c, c1, h1hi[np], h1lo[np]};
    CellArgs l0 = {Xhi + (size_t)(s + 1) * F_, Xlo + (size_t)(s + 1) * F_, S_ * F_, 64, W0cp,
                   h0hi[np], h0lo[np], Whh0p, b0c, c0, h0hi[pp], h0lo[pp]};
    lstm3_dual<<<grid2, 512, 0, stream>>>(l1, l0);
  }
  // L1(167): pp=1,np=0 — reads h0[0], h1[1], writes h1[0]
  {
    CellArgs l1 = {h0hi[0], h0lo[0], 512, 512, Wih1p,
                   h1hi[1], h1lo[1], Whh1p, b1c, c1, h1hi[0], h1lo[0]};
    lstm3<<<grid, 512, 0, stream>>>(l1);
  }

  // ---- decoder + autoregressive phase ----
  // per step s (167..190): { dec(s) , L0(s+1) } fused (both children of L1(s)),
  // then L1(s+1) single. Last decoder has no companion.
  for (int s = S_ - 1; s < S_ + PRED - 1; ++s) {
    int pp = s & 1, np = 1 - pp;
    DecArgs d = {h1hi[np], h1lo[np], Wdec, bdec, out + (size_t)(s - (S_ - 1)) * F_};
    if (s + 1 < S_ + PRED - 1) {
      // L0(s+1): pp'=np, np'=pp — A1=h1[np], A2=h0[np], writes h0[pp]
      CellArgs l0 = {h1hi[np], h1lo[np], 512, 512, W0cdp,
                     h0hi[np], h0lo[np], Whh0p, b0ar, c0, h0hi[pp], h0lo[pp]};
      lstm3_cell_dec<<<grid2, 512, 0, stream>>>(l0, d);
      // L1(s+1): A1=h0[pp], A2=h1[np], writes h1[pp]
      CellArgs l1 = {h0hi[pp], h0lo[pp], 512, 512, Wih1p,
                     h1hi[np], h1lo[np], Whh1p, b1c, c1, h1hi[pp], h1lo[pp]};
      lstm3<<<grid, 512, 0, stream>>>(l1);
    } else {
      k_decoder2<<<dim3(16, 8), 512, 0, stream>>>(d);
    }
  }
}